// Round 6
// baseline (192.745 us; speedup 1.0000x reference)
//
#include <hip/hip_runtime.h>
#include <hip/hip_cooperative_groups.h>
namespace cg = cooperative_groups;

#define BATCH 2
#define L_SEQ 2048
#define DI 2048
#define NROW (BATCH * L_SEQ)   // 4096
#define E_DIM 96
#define RNK 64                 // DT_RANK
#define NST 16                 // D_STATE
#define CLEN 64                // chunk length (fused path)
#define NCHG 32                // chunks (fused path)
#define NCH 64                 // chunks (fallback path)
#define CL 32                  // chunk length (fallback path)
#define SPLITK 16              // K1 split-K factor
#define KSL (DI / SPLITK)      // 128 k per split

// ---------------- workspace layout (floats) ----------------
// xdbl     : [NROW][96]                    @0        (393216)
// partials : [SPLITK][NROW][96]            @393216   (6291456), dead after K1b
//   hloc32 : [B][32][NST][DI]              @393216   (2097152)  fused P1->P2
//   dsum32 : [B][32][DI]                   @2490368  (131072)   fused P1->P2
//   hloc64 : [B][64][NST][DI]              @393216   (4194304)  fallback C->S2
//   dsum64 : [B][64][DI]                   @4587520  (262144)   fallback C->S2
// hent32  : [B][32][NST][DI]               @6684672  (2097152)  fused P2->P3
// hent64  : [B][64][NST][DI]               @6684672  (4194304)  fallback S2->S3
// wdtT    : [RNK][DI]                      @8781824  (131072)   K1b -> consumers
//   (inside hent64 tail: lifetime-disjoint — C reads wdtT before S2 writes hent64)
#define WS_XDBL 0
#define WS_PART 393216
#define WS_HLOC32 393216
#define WS_DSUM32 2490368
#define WS_HENT32 6684672
#define WS_HLOC64 393216
#define WS_DSUM64 4587520
#define WS_HENT64 6684672
#define WS_WDTT 8781824

__device__ __forceinline__ float softplusf(float z) {
    return fmaxf(z, 0.f) + __logf(1.f + __expf(-fabsf(z)));
}

// raw barrier: LDS-visibility only (lgkmcnt), does NOT drain vmcnt.
__device__ __forceinline__ void barrier_lds() {
    asm volatile("s_waitcnt lgkmcnt(0)" ::: "memory");
    __builtin_amdgcn_s_barrier();
}

// ===== K1a: partial[s] = x[:, ksl] @ W^T slice (proven round-4) =====
__global__ __launch_bounds__(256) void gemm_xproj_part(const float* __restrict__ x,
                                                       const float* __restrict__ Wx,
                                                       float* __restrict__ part) {
    __shared__ float xs[32][68];
    __shared__ float wsh[32][100];
    const int tid = threadIdx.x;
    const int r0 = blockIdx.x * 64;
    const int kbase0 = blockIdx.y * KSL;
    const int rg = tid >> 4;
    const int cg = tid & 15;

    float acc[4][6];
#pragma unroll
    for (int i = 0; i < 4; i++)
#pragma unroll
        for (int j = 0; j < 6; j++) acc[i][j] = 0.f;

    for (int kt = 0; kt < KSL / 32; kt++) {
        const int kb = kbase0 + kt * 32;
#pragma unroll
        for (int rep = 0; rep < 2; rep++) {
            int i = rep * 256 + tid;
            int row = i >> 3;
            int kq = i & 7;
            float4 v = *(const float4*)&x[(long)(r0 + row) * DI + kb + kq * 4];
            xs[kq * 4 + 0][row] = v.x;
            xs[kq * 4 + 1][row] = v.y;
            xs[kq * 4 + 2][row] = v.z;
            xs[kq * 4 + 3][row] = v.w;
        }
#pragma unroll
        for (int rep = 0; rep < 3; rep++) {
            int i = rep * 256 + tid;
            int e = i >> 3;
            int kq = i & 7;
            float4 v = *(const float4*)&Wx[(long)e * DI + kb + kq * 4];
            wsh[kq * 4 + 0][e] = v.x;
            wsh[kq * 4 + 1][e] = v.y;
            wsh[kq * 4 + 2][e] = v.z;
            wsh[kq * 4 + 3][e] = v.w;
        }
        __syncthreads();
#pragma unroll 8
        for (int k = 0; k < 32; k++) {
            float xr[4], wr[6];
#pragma unroll
            for (int i = 0; i < 4; i++) xr[i] = xs[k][rg * 4 + i];
#pragma unroll
            for (int j = 0; j < 6; j++) wr[j] = wsh[k][cg * 6 + j];
#pragma unroll
            for (int i = 0; i < 4; i++)
#pragma unroll
                for (int j = 0; j < 6; j++) acc[i][j] = fmaf(xr[i], wr[j], acc[i][j]);
        }
        __syncthreads();
    }
    const long sbase = (long)blockIdx.y * NROW * E_DIM;
#pragma unroll
    for (int i = 0; i < 4; i++) {
        long rowb = sbase + (long)(r0 + rg * 4 + i) * E_DIM + cg * 6;
#pragma unroll
        for (int j = 0; j < 6; j++) part[rowb + j] = acc[i][j];
    }
}

// ===== K1b: xdbl = sum over splits + WdtT transpose (proven round-4) =====
__global__ __launch_bounds__(256) void xproj_reduce_wt(const float* __restrict__ part,
                                                       float* __restrict__ xdbl,
                                                       const float* __restrict__ Wdt,
                                                       float* __restrict__ wdtT) {
    if (blockIdx.x < 384) {
        const int i4 = blockIdx.x * 256 + threadIdx.x;
        const float4* p4 = (const float4*)part;
        float4 s = p4[i4];
#pragma unroll
        for (int sp = 1; sp < SPLITK; sp++) {
            float4 v = p4[(long)sp * (NROW * E_DIM / 4) + i4];
            s.x += v.x; s.y += v.y; s.z += v.z; s.w += v.w;
        }
        ((float4*)xdbl)[i4] = s;
    } else {
        const int t = (blockIdx.x - 384) * 256 + threadIdx.x;
        const int base = t * 4;
        const int r = base >> 11;
        const int d4 = base & (DI - 1);
        float4 o;
        o.x = Wdt[(long)(d4 + 0) * RNK + r];
        o.y = Wdt[(long)(d4 + 1) * RNK + r];
        o.z = Wdt[(long)(d4 + 2) * RNK + r];
        o.w = Wdt[(long)(d4 + 3) * RNK + r];
        *(float4*)&wdtT[base] = o;
    }
}

#define PW 260   // wt pitch (floats)
#define PD 36    // fallback dlb pitch
#define PDF 68   // fused dlb pitch (64 rows + 4 pad)

// power chain: e_[n] = p1^(n+1), 1 exp + 15 mul (A[n] == (n+1)*A0)
#define PCHAIN_E16(DCV) \
    float p1 = __expf((DCV) * A0); \
    float p2 = p1 * p1, p3 = p2 * p1, p4 = p2 * p2, p5 = p4 * p1; \
    float p6 = p3 * p3, p7 = p4 * p3, p8 = p4 * p4; \
    float e_[16] = {p1, p2, p3, p4, p5, p6, p7, p8, \
                    p8 * p1, p5 * p5, p8 * p3, p6 * p6, \
                    p8 * p5, p7 * p7, p8 * p7, p8 * p8};

// ===== fused C+S2+S3: cooperative, 512 blocks x 256 thr =====
// LDS = single 5248-float union (20.5 KB): {wt+dlb} -> {dtt16} -> {bsm+csm}.
// 2 blocks/CU co-resident (VGPR<=256 via launch_bounds; LDS gives >=3 even
// under a 64KB/CU occupancy model) -> 512-block cooperative grid validates.
__global__ __launch_bounds__(256, 2) void ssm_fused(const float* __restrict__ x,
                                                    const float* __restrict__ xdbl,
                                                    const float* __restrict__ wdtT,
                                                    const float* __restrict__ b_dt,
                                                    const float* __restrict__ A_log,
                                                    const float* __restrict__ Dp,
                                                    float* __restrict__ hloc,
                                                    float* __restrict__ dsumb,
                                                    float* __restrict__ hent,
                                                    float* __restrict__ out) {
    __shared__ float region[16 * PW + 16 * PDF];   // 5248 floats = 20992 B
    float* wt  = region;                 // [16][PW]  (GEMM phase)
    float* dlb = region + 16 * PW;       // [16][PDF] (GEMM phase)
    float* dtt = region;                 // [16][256] (transpose rounds; 4096 fl)
    float* bsm = region;                 // [64][16]  (scan/P3; 1024 fl)
    float* csm = region + CLEN * NST;    // [64][16]  (P3; 1024 fl)

    const int tid = threadIdx.x;
    const int bid = blockIdx.x;            // 0..511
    const int d0 = (bid & 7) * 256;
    const int c = (bid >> 3) & 31;
    const int b = bid >> 8;
    const int row0 = b * L_SEQ + c * CLEN;
    const int d = d0 + tid;
    const int rg = tid >> 6;               // wave id (rows rg*8..rg*8+7 per half)
    const int cg = tid & 63;               // 4 cols each

    // ---------- P1: delta-GEMM (K=64, 4 reg-dbuf quarters) ----------
    float4 wq[2][4]; float4 dq[2];
#define ISSUE_Q(SET, Q) \
    { _Pragma("unroll") \
      for (int rep = 0; rep < 4; rep++) { \
          int i = rep * 256 + tid; int kk = i >> 6, c4 = i & 63; \
          wq[SET][rep] = *(const float4*)&wdtT[(long)((Q) * 16 + kk) * DI + d0 + c4 * 4]; } \
      { int r = tid >> 2, kk = tid & 3; \
        dq[SET] = *(const float4*)&xdbl[(long)(row0 + r) * E_DIM + (Q) * 16 + kk * 4]; } }
#define WRITE_Q(SET) \
    { _Pragma("unroll") \
      for (int rep = 0; rep < 4; rep++) { \
          int i = rep * 256 + tid; int kk = i >> 6, c4 = i & 63; \
          *(float4*)&wt[kk * PW + c4 * 4] = wq[SET][rep]; } \
      { int r = tid >> 2, kk = tid & 3; \
        dlb[(kk * 4 + 0) * PDF + r] = dq[SET].x; \
        dlb[(kk * 4 + 1) * PDF + r] = dq[SET].y; \
        dlb[(kk * 4 + 2) * PDF + r] = dq[SET].z; \
        dlb[(kk * 4 + 3) * PDF + r] = dq[SET].w; } }

    ISSUE_Q(0, 0);
    float4 av[4];
#pragma unroll
    for (int q = 0; q < 4; q++)
        av[q] = *(const float4*)&A_log[(long)d * NST + q * 4];
    float4 bb = *(const float4*)&b_dt[d0 + cg * 4];

    WRITE_Q(0);
    ISSUE_Q(1, 1);
    barrier_lds();

    float accA[8][4], accB[8][4];
#pragma unroll
    for (int i = 0; i < 8; i++)
#pragma unroll
        for (int j = 0; j < 4; j++) { accA[i][j] = 0.f; accB[i][j] = 0.f; }

#pragma unroll
    for (int qq = 0; qq < 4; qq++) {
#pragma unroll
        for (int k = 0; k < 16; k++) {
            float4 a0 = *(const float4*)&dlb[k * PDF + rg * 8];
            float4 a1 = *(const float4*)&dlb[k * PDF + rg * 8 + 4];
            float4 b0 = *(const float4*)&dlb[k * PDF + 32 + rg * 8];
            float4 b1 = *(const float4*)&dlb[k * PDF + 32 + rg * 8 + 4];
            float4 w4 = *(const float4*)&wt[k * PW + cg * 4];
            float ar[8] = {a0.x, a0.y, a0.z, a0.w, a1.x, a1.y, a1.z, a1.w};
            float br[8] = {b0.x, b0.y, b0.z, b0.w, b1.x, b1.y, b1.z, b1.w};
            float wr[4] = {w4.x, w4.y, w4.z, w4.w};
#pragma unroll
            for (int i = 0; i < 8; i++)
#pragma unroll
                for (int j = 0; j < 4; j++) {
                    accA[i][j] = fmaf(ar[i], wr[j], accA[i][j]);
                    accB[i][j] = fmaf(br[i], wr[j], accB[i][j]);
                }
        }
        barrier_lds();                    // all reads of this quarter done
        if (qq < 3) {
            WRITE_Q((qq + 1) & 1);
            if (qq < 2) ISSUE_Q(qq & 1, qq + 2);
            barrier_lds();                // staged quarter visible
        }
    }

    // x column prefetch: lands under the transpose rounds
    float xv[CLEN];
#pragma unroll
    for (int ll = 0; ll < CLEN; ll++) xv[ll] = x[(long)(row0 + ll) * DI + d];

    // A params: fast path iff A[n] == (n+1)*A0
    float A0; bool fast;
    {
        float a16[16];
#pragma unroll
        for (int q = 0; q < 4; q++) {
            a16[q * 4 + 0] = -__expf(av[q].x);
            a16[q * 4 + 1] = -__expf(av[q].y);
            a16[q * 4 + 2] = -__expf(av[q].z);
            a16[q * 4 + 3] = -__expf(av[q].w);
        }
        A0 = a16[0];
        fast = true;
#pragma unroll
        for (int n = 1; n < 16; n++)
            fast = fast && (fabsf(a16[n] - (float)(n + 1) * A0) <= 1e-4f * (float)(n + 1));
    }

    // transpose rounds: 16 delta rows at a time through dtt (region overlay)
    float dcl[CLEN];
#define XROUND(ACC, RG0, TBASE) \
    if (rg == (RG0) || rg == (RG0) + 1) { \
        _Pragma("unroll") for (int i = 0; i < 8; i++) { \
            float4 o; \
            o.x = softplusf(ACC[i][0] + bb.x); \
            o.y = softplusf(ACC[i][1] + bb.y); \
            o.z = softplusf(ACC[i][2] + bb.z); \
            o.w = softplusf(ACC[i][3] + bb.w); \
            *(float4*)&dtt[((rg - (RG0)) * 8 + i) * 256 + cg * 4] = o; \
        } \
    } \
    barrier_lds(); \
    _Pragma("unroll") for (int ll = 0; ll < 16; ll++) dcl[(TBASE) + ll] = dtt[ll * 256 + tid]; \
    barrier_lds();

    XROUND(accA, 0, 0)     // rows  0..15
    XROUND(accA, 2, 16)    // rows 16..31
    XROUND(accB, 0, 32)    // rows 32..47
    XROUND(accB, 2, 48)    // rows 48..63

    // stage B/C rows for the whole chunk (overlay region; dtt dead)
    { int r = tid >> 2, q = tid & 3;
      float4 bv = *(const float4*)&xdbl[(long)(row0 + r) * E_DIM + 64 + q * 4];
      float4 cv = *(const float4*)&xdbl[(long)(row0 + r) * E_DIM + 80 + q * 4];
      *(float4*)&bsm[r * NST + q * 4] = bv;
      *(float4*)&csm[r * NST + q * 4] = cv; }
    barrier_lds();

    // chunk-local scan
    float h[16];
#pragma unroll
    for (int n = 0; n < 16; n++) h[n] = 0.f;
    float dsum = 0.f;
    if (fast) {
#pragma unroll
        for (int ll = 0; ll < CLEN; ll++) {
            float dcv = dcl[ll]; float du = dcv * xv[ll];
            PCHAIN_E16(dcv);
#pragma unroll
            for (int q = 0; q < 4; q++) {
                float4 v = *(const float4*)&bsm[ll * NST + q * 4];
                h[q * 4 + 0] = fmaf(e_[q * 4 + 0], h[q * 4 + 0], du * v.x);
                h[q * 4 + 1] = fmaf(e_[q * 4 + 1], h[q * 4 + 1], du * v.y);
                h[q * 4 + 2] = fmaf(e_[q * 4 + 2], h[q * 4 + 2], du * v.z);
                h[q * 4 + 3] = fmaf(e_[q * 4 + 3], h[q * 4 + 3], du * v.w);
            }
            dsum += dcv;
        }
    } else {
        float Ag[16];
#pragma unroll
        for (int q = 0; q < 4; q++) {
            Ag[q * 4 + 0] = -__expf(av[q].x); Ag[q * 4 + 1] = -__expf(av[q].y);
            Ag[q * 4 + 2] = -__expf(av[q].z); Ag[q * 4 + 3] = -__expf(av[q].w);
        }
#pragma unroll
        for (int ll = 0; ll < CLEN; ll++) {
            float dcv = dcl[ll]; float du = dcv * xv[ll];
#pragma unroll
            for (int q = 0; q < 4; q++) {
                float4 v = *(const float4*)&bsm[ll * NST + q * 4];
                h[q * 4 + 0] = fmaf(__expf(dcv * Ag[q * 4 + 0]), h[q * 4 + 0], du * v.x);
                h[q * 4 + 1] = fmaf(__expf(dcv * Ag[q * 4 + 1]), h[q * 4 + 1], du * v.y);
                h[q * 4 + 2] = fmaf(__expf(dcv * Ag[q * 4 + 2]), h[q * 4 + 2], du * v.z);
                h[q * 4 + 3] = fmaf(__expf(dcv * Ag[q * 4 + 3]), h[q * 4 + 3], du * v.w);
            }
            dsum += dcv;
        }
    }
    const long cbq = (long)(b * NCHG + c);
#pragma unroll
    for (int n = 0; n < 16; n++)
        hloc[(cbq * NST + n) * DI + d] = h[n];
    dsumb[cbq * DI + d] = dsum;

    __threadfence();
    cg::this_grid().sync();

    // ---------- P2: prefix over 32 chunks (65536 chains, 8-tiled) ----------
    {
        const int gi = bid * 256 + tid;
        if (gi < BATCH * DI * NST) {
            const int d2 = gi & (DI - 1);
            const int n2 = (gi >> 11) & 15;
            const int b2 = gi >> 15;
            const float An = -__expf(A_log[(long)d2 * NST + n2]);
            float hc = 0.f;
#pragma unroll
            for (int c8 = 0; c8 < NCHG; c8 += 8) {
                float hl[8], ds8[8];
#pragma unroll
                for (int j = 0; j < 8; j++) {
                    hl[j] = hloc[((long)(b2 * NCHG + c8 + j) * NST + n2) * DI + d2];
                    ds8[j] = dsumb[(long)(b2 * NCHG + c8 + j) * DI + d2];
                }
#pragma unroll
                for (int j = 0; j < 8; j++) {
                    hent[((long)(b2 * NCHG + c8 + j) * NST + n2) * DI + d2] = hc;
                    hc = fmaf(__expf(An * ds8[j]), hc, hl[j]);
                }
            }
        }
    }
    __threadfence();
    cg::this_grid().sync();

    // ---------- P3: output pass from registers (bsm/csm persist in LDS) ----------
    const float Dd = Dp[d];
#pragma unroll
    for (int n = 0; n < 16; n++)
        h[n] = hent[(cbq * NST + n) * DI + d];

    if (fast) {
#pragma unroll
        for (int ll = 0; ll < CLEN; ll++) {
            float dcv = dcl[ll]; float xc = xv[ll]; float du = dcv * xc;
            PCHAIN_E16(dcv);
            float y = 0.f;
#pragma unroll
            for (int q = 0; q < 4; q++) {
                float4 v = *(const float4*)&bsm[ll * NST + q * 4];
                float4 w = *(const float4*)&csm[ll * NST + q * 4];
                h[q * 4 + 0] = fmaf(e_[q * 4 + 0], h[q * 4 + 0], du * v.x);
                h[q * 4 + 1] = fmaf(e_[q * 4 + 1], h[q * 4 + 1], du * v.y);
                h[q * 4 + 2] = fmaf(e_[q * 4 + 2], h[q * 4 + 2], du * v.z);
                h[q * 4 + 3] = fmaf(e_[q * 4 + 3], h[q * 4 + 3], du * v.w);
                y = fmaf(h[q * 4 + 0], w.x, y);
                y = fmaf(h[q * 4 + 1], w.y, y);
                y = fmaf(h[q * 4 + 2], w.z, y);
                y = fmaf(h[q * 4 + 3], w.w, y);
            }
            out[(long)(row0 + ll) * DI + d] = fmaf(xc, Dd, y);
        }
    } else {
        float Ag[16];
#pragma unroll
        for (int q = 0; q < 4; q++) {
            Ag[q * 4 + 0] = -__expf(av[q].x); Ag[q * 4 + 1] = -__expf(av[q].y);
            Ag[q * 4 + 2] = -__expf(av[q].z); Ag[q * 4 + 3] = -__expf(av[q].w);
        }
#pragma unroll
        for (int ll = 0; ll < CLEN; ll++) {
            float dcv = dcl[ll]; float xc = xv[ll]; float du = dcv * xc;
            float y = 0.f;
#pragma unroll
            for (int q = 0; q < 4; q++) {
                float4 v = *(const float4*)&bsm[ll * NST + q * 4];
                float4 w = *(const float4*)&csm[ll * NST + q * 4];
                h[q * 4 + 0] = fmaf(__expf(dcv * Ag[q * 4 + 0]), h[q * 4 + 0], du * v.x);
                h[q * 4 + 1] = fmaf(__expf(dcv * Ag[q * 4 + 1]), h[q * 4 + 1], du * v.y);
                h[q * 4 + 2] = fmaf(__expf(dcv * Ag[q * 4 + 2]), h[q * 4 + 2], du * v.z);
                h[q * 4 + 3] = fmaf(__expf(dcv * Ag[q * 4 + 3]), h[q * 4 + 3], du * v.w);
                y = fmaf(h[q * 4 + 0], w.x, y);
                y = fmaf(h[q * 4 + 1], w.y, y);
                y = fmaf(h[q * 4 + 2], w.z, y);
                y = fmaf(h[q * 4 + 3], w.w, y);
            }
            out[(long)(row0 + ll) * DI + d] = fmaf(xc, Dd, y);
        }
    }
}

// ===== FALLBACK path: round-4-proven C/S2/S3 trio =====
__global__ __launch_bounds__(256) void gemm_dt_scan(const float* __restrict__ x,
                                                    const float* __restrict__ xdbl,
                                                    const float* __restrict__ wdtT,
                                                    const float* __restrict__ b_dt,
                                                    const float* __restrict__ A_log,
                                                    float* __restrict__ delta,
                                                    float* __restrict__ hloc,
                                                    float* __restrict__ dsumb) {
    __shared__ float region[32 * PW + 32 * PD];
    __shared__ float bsm[CL * NST];
    float* wt  = region;
    float* dlb = region + 32 * PW;
    float* dtt = region;

    const int tid = threadIdx.x;
    const int d0 = blockIdx.x * 256;
    const int c = blockIdx.y;
    const int b = blockIdx.z;
    const int row0 = b * L_SEQ + c * CL;
    const int d = d0 + tid;
    const int rg = tid >> 6;
    const int cg = tid & 63;

    if (tid < 128) {
        int r = tid >> 2, q = tid & 3;
        ((float4*)bsm)[tid] = *(const float4*)&xdbl[(long)(row0 + r) * E_DIM + 64 + q * 4];
    }

    float acc[8][4];
#pragma unroll
    for (int i = 0; i < 8; i++)
#pragma unroll
        for (int j = 0; j < 4; j++) acc[i][j] = 0.f;

    float xvv[CL];
    float4 av[4];

#pragma unroll
    for (int kt = 0; kt < 2; kt++) {
        const int kb = kt * 32;
#pragma unroll
        for (int rep = 0; rep < 8; rep++) {
            int i = rep * 256 + tid;
            int k = i >> 6, c4 = i & 63;
            float4 v = *(const float4*)&wdtT[(long)(kb + k) * DI + d0 + c4 * 4];
            *(float4*)&wt[k * PW + c4 * 4] = v;
        }
        {
            int r = tid >> 3, kq = tid & 7;
            float4 v = *(const float4*)&xdbl[(long)(row0 + r) * E_DIM + kb + kq * 4];
            dlb[(kq * 4 + 0) * PD + r] = v.x;
            dlb[(kq * 4 + 1) * PD + r] = v.y;
            dlb[(kq * 4 + 2) * PD + r] = v.z;
            dlb[(kq * 4 + 3) * PD + r] = v.w;
        }
        if (kt == 0) {
#pragma unroll
            for (int ll = 0; ll < CL; ll++)
                xvv[ll] = x[(long)(row0 + ll) * DI + d];
#pragma unroll
            for (int q = 0; q < 4; q++)
                av[q] = *(const float4*)&A_log[(long)d * NST + q * 4];
        }
        barrier_lds();
#pragma unroll 8
        for (int k = 0; k < 32; k++) {
            float4 xa = *(const float4*)&dlb[k * PD + rg * 8];
            float4 xb = *(const float4*)&dlb[k * PD + rg * 8 + 4];
            float4 wv4 = *(const float4*)&wt[k * PW + cg * 4];
            float xr[8] = {xa.x, xa.y, xa.z, xa.w, xb.x, xb.y, xb.z, xb.w};
            float wr[4] = {wv4.x, wv4.y, wv4.z, wv4.w};
#pragma unroll
            for (int i = 0; i < 8; i++)
#pragma unroll
                for (int j = 0; j < 4; j++) acc[i][j] = fmaf(xr[i], wr[j], acc[i][j]);
        }
        barrier_lds();
    }

    float4 bbf = *(const float4*)&b_dt[d0 + cg * 4];
#pragma unroll
    for (int i = 0; i < 8; i++) {
        int r = rg * 8 + i;
        float4 o;
        o.x = softplusf(acc[i][0] + bbf.x);
        o.y = softplusf(acc[i][1] + bbf.y);
        o.z = softplusf(acc[i][2] + bbf.z);
        o.w = softplusf(acc[i][3] + bbf.w);
        *(float4*)&delta[(long)(row0 + r) * DI + d0 + cg * 4] = o;
        *(float4*)&dtt[r * 256 + cg * 4] = o;
    }

    float A[16];
#pragma unroll
    for (int q = 0; q < 4; q++) {
        A[q * 4 + 0] = -__expf(av[q].x);
        A[q * 4 + 1] = -__expf(av[q].y);
        A[q * 4 + 2] = -__expf(av[q].z);
        A[q * 4 + 3] = -__expf(av[q].w);
    }
    const float A0 = A[0];
    bool fast = true;
#pragma unroll
    for (int n = 1; n < 16; n++)
        fast = fast && (fabsf(A[n] - (float)(n + 1) * A0) <= 1e-4f * (float)(n + 1));
    barrier_lds();

    float h[16];
#pragma unroll
    for (int n = 0; n < 16; n++) h[n] = 0.f;
    float dsum = 0.f;
    if (fast) {
        for (int ll = 0; ll < CL; ll++) {
            float dc = dtt[ll * 256 + tid];
            float du = dc * xvv[ll];
            PCHAIN_E16(dc);
#pragma unroll
            for (int q = 0; q < 4; q++) {
                float4 v = *(const float4*)&bsm[ll * NST + q * 4];
                h[q * 4 + 0] = fmaf(e_[q * 4 + 0], h[q * 4 + 0], du * v.x);
                h[q * 4 + 1] = fmaf(e_[q * 4 + 1], h[q * 4 + 1], du * v.y);
                h[q * 4 + 2] = fmaf(e_[q * 4 + 2], h[q * 4 + 2], du * v.z);
                h[q * 4 + 3] = fmaf(e_[q * 4 + 3], h[q * 4 + 3], du * v.w);
            }
            dsum += dc;
        }
    } else {
        for (int ll = 0; ll < CL; ll++) {
            float dc = dtt[ll * 256 + tid];
            float du = dc * xvv[ll];
#pragma unroll
            for (int q = 0; q < 4; q++) {
                float4 v = *(const float4*)&bsm[ll * NST + q * 4];
                h[q * 4 + 0] = fmaf(__expf(dc * A[q * 4 + 0]), h[q * 4 + 0], du * v.x);
                h[q * 4 + 1] = fmaf(__expf(dc * A[q * 4 + 1]), h[q * 4 + 1], du * v.y);
                h[q * 4 + 2] = fmaf(__expf(dc * A[q * 4 + 2]), h[q * 4 + 2], du * v.z);
                h[q * 4 + 3] = fmaf(__expf(dc * A[q * 4 + 3]), h[q * 4 + 3], du * v.w);
            }
            dsum += dc;
        }
    }
    const long cb = (long)(b * NCH + c);
#pragma unroll
    for (int n = 0; n < 16; n++)
        hloc[(cb * NST + n) * DI + d] = h[n];
    dsumb[cb * DI + d] = dsum;
}

__global__ __launch_bounds__(256, 1) void scan_prefix(const float* __restrict__ A_log,
                                                      const float* __restrict__ hloc,
                                                      const float* __restrict__ dsumb,
                                                      float* __restrict__ hent) {
    const int g = blockIdx.x * 256 + threadIdx.x;
    const int d = g & (DI - 1);
    const int n = (g >> 11) & 15;
    const int b = g >> 15;
    const float An = -__expf(A_log[(long)d * NST + n]);
    float hl[NCH], dsv[NCH];
#pragma unroll
    for (int cc = 0; cc < NCH; cc++) {
        hl[cc]  = hloc[((long)(b * NCH + cc) * NST + n) * DI + d];
        dsv[cc] = dsumb[(long)(b * NCH + cc) * DI + d];
    }
    float e[NCH];
#pragma unroll
    for (int cc = 0; cc < NCH; cc++) e[cc] = __expf(An * dsv[cc]);
    float hc = 0.f;
#pragma unroll
    for (int cc = 0; cc < NCH; cc++) {
        hent[((long)(b * NCH + cc) * NST + n) * DI + d] = hc;
        hc = fmaf(e[cc], hc, hl[cc]);
    }
}

__global__ __launch_bounds__(256) void scan_out(const float* __restrict__ x,
                                                const float* __restrict__ xdbl,
                                                const float* __restrict__ A_log,
                                                const float* __restrict__ Dp,
                                                const float* __restrict__ hent,
                                                float* __restrict__ out) {
    __shared__ float bsm[CL * NST];
    __shared__ float csm[CL * NST];
    const int tid = threadIdx.x;
    const int d0 = blockIdx.x * 256;
    const int c = blockIdx.y;
    const int b = blockIdx.z;
    const int row0 = b * L_SEQ + c * CL;
    const int d = d0 + tid;

    {
        int i = tid & 127, r = i >> 2, q = i & 3;
        float4 v = *(const float4*)&xdbl[(long)(row0 + r) * E_DIM + 64 + ((tid >> 7) << 4) + q * 4];
        if (tid < 128) ((float4*)bsm)[i] = v;
        else           ((float4*)csm)[i] = v;
    }
    __syncthreads();

    float4 av[4];
#pragma unroll
    for (int q = 0; q < 4; q++)
        av[q] = *(const float4*)&A_log[(long)d * NST + q * 4];
    const long cb = (long)(b * NCH + c);
    float hv[16];
#pragma unroll
    for (int n = 0; n < 16; n++)
        hv[n] = hent[(cb * NST + n) * DI + d];
    const float Dd = Dp[d];

    float dv[CL], xvv[CL];
#pragma unroll
    for (int ll = 0; ll < CL; ll++) {
        dv[ll] = out[(long)(row0 + ll) * DI + d];
        xvv[ll] = x[(long)(row0 + ll) * DI + d];
    }

    float A[16];
#pragma unroll
    for (int q = 0; q < 4; q++) {
        A[q * 4 + 0] = -__expf(av[q].x);
        A[q * 4 + 1] = -__expf(av[q].y);
        A[q * 4 + 2] = -__expf(av[q].z);
        A[q * 4 + 3] = -__expf(av[q].w);
    }
    const float A0 = A[0];
    bool fast = true;
#pragma unroll
    for (int n = 1; n < 16; n++)
        fast = fast && (fabsf(A[n] - (float)(n + 1) * A0) <= 1e-4f * (float)(n + 1));
    float h[16];
#pragma unroll
    for (int n = 0; n < 16; n++) h[n] = hv[n];

    long idx = (long)row0 * DI + d;
    if (fast) {
        for (int ll = 0; ll < CL; ll++) {
            float dc = dv[ll];
            float xc = xvv[ll];
            float du = dc * xc;
            PCHAIN_E16(dc);
            float y = 0.f;
#pragma unroll
            for (int q = 0; q < 4; q++) {
                float4 v = *(const float4*)&bsm[ll * NST + q * 4];
                float4 w = *(const float4*)&csm[ll * NST + q * 4];
                h[q * 4 + 0] = fmaf(e_[q * 4 + 0], h[q * 4 + 0], du * v.x);
                h[q * 4 + 1] = fmaf(e_[q * 4 + 1], h[q * 4 + 1], du * v.y);
                h[q * 4 + 2] = fmaf(e_[q * 4 + 2], h[q * 4 + 2], du * v.z);
                h[q * 4 + 3] = fmaf(e_[q * 4 + 3], h[q * 4 + 3], du * v.w);
                y = fmaf(h[q * 4 + 0], w.x, y);
                y = fmaf(h[q * 4 + 1], w.y, y);
                y = fmaf(h[q * 4 + 2], w.z, y);
                y = fmaf(h[q * 4 + 3], w.w, y);
            }
            out[idx] = fmaf(xc, Dd, y);
            idx += DI;
        }
    } else {
        for (int ll = 0; ll < CL; ll++) {
            float dc = dv[ll];
            float xc = xvv[ll];
            float du = dc * xc;
            float y = 0.f;
#pragma unroll
            for (int q = 0; q < 4; q++) {
                float4 v = *(const float4*)&bsm[ll * NST + q * 4];
                float4 w = *(const float4*)&csm[ll * NST + q * 4];
                h[q * 4 + 0] = fmaf(__expf(dc * A[q * 4 + 0]), h[q * 4 + 0], du * v.x);
                h[q * 4 + 1] = fmaf(__expf(dc * A[q * 4 + 1]), h[q * 4 + 1], du * v.y);
                h[q * 4 + 2] = fmaf(__expf(dc * A[q * 4 + 2]), h[q * 4 + 2], du * v.z);
                h[q * 4 + 3] = fmaf(__expf(dc * A[q * 4 + 3]), h[q * 4 + 3], du * v.w);
                y = fmaf(h[q * 4 + 0], w.x, y);
                y = fmaf(h[q * 4 + 1], w.y, y);
                y = fmaf(h[q * 4 + 2], w.z, y);
                y = fmaf(h[q * 4 + 3], w.w, y);
            }
            out[idx] = fmaf(xc, Dd, y);
            idx += DI;
        }
    }
}

extern "C" void kernel_launch(void* const* d_in, const int* in_sizes, int n_in,
                              void* d_out, int out_size, void* d_ws, size_t ws_size,
                              hipStream_t stream) {
    const float* x    = (const float*)d_in[0];
    const float* Wx   = (const float*)d_in[1];
    const float* Wdt  = (const float*)d_in[2];
    const float* bdt  = (const float*)d_in[3];
    const float* Alog = (const float*)d_in[4];
    const float* Dp   = (const float*)d_in[5];
    float* out = (float*)d_out;
    float* ws = (float*)d_ws;
    float* xdbl   = ws + WS_XDBL;
    float* partb  = ws + WS_PART;
    float* wdtT   = ws + WS_WDTT;
    float* hloc32 = ws + WS_HLOC32;
    float* dsum32 = ws + WS_DSUM32;
    float* hent32 = ws + WS_HENT32;
    float* hloc64 = ws + WS_HLOC64;
    float* dsum64 = ws + WS_DSUM64;
    float* hent64 = ws + WS_HENT64;

    // one-time capacity check (host-side queries only; graph-capture-safe)
    static int coop_ok = -1;
    if (coop_ok < 0) {
        int nb = 0, ncu = 0, dev = 0;
        (void)hipGetDevice(&dev);
        hipError_t e1 = hipOccupancyMaxActiveBlocksPerMultiprocessor(
            &nb, (const void*)ssm_fused, 256, 0);
        hipError_t e2 = hipDeviceGetAttribute(
            &ncu, hipDeviceAttributeMultiprocessorCount, dev);
        coop_ok = (e1 == hipSuccess && e2 == hipSuccess &&
                   (long)nb * ncu >= BATCH * NCHG * 8) ? 1 : 0;
    }

    gemm_xproj_part<<<dim3(NROW / 64, SPLITK), 256, 0, stream>>>(x, Wx, partb);
    xproj_reduce_wt<<<dim3(512), 256, 0, stream>>>(partb, xdbl, Wdt, wdtT);

    bool done = false;
    if (coop_ok == 1) {
        void* args[] = {(void*)&x, (void*)&xdbl, (void*)&wdtT, (void*)&bdt, (void*)&Alog,
                        (void*)&Dp, (void*)&hloc32, (void*)&dsum32, (void*)&hent32, (void*)&out};
        hipError_t le = hipLaunchCooperativeKernel((const void*)ssm_fused,
                                                   dim3(BATCH * NCHG * 8), dim3(256),
                                                   args, 0, stream);
        done = (le == hipSuccess);
    }
    if (!done) {
        gemm_dt_scan<<<dim3(DI / 256, NCH, BATCH), 256, 0, stream>>>(x, xdbl, wdtT, bdt, Alog,
                                                                     out, hloc64, dsum64);
        scan_prefix<<<dim3(BATCH * DI * NST / 256), 256, 0, stream>>>(Alog, hloc64, dsum64, hent64);
        scan_out<<<dim3(DI / 256, NCH, BATCH), 256, 0, stream>>>(x, xdbl, Alog, Dp, hent64, out);
    }
}